// Round 6
// baseline (266.617 us; speedup 1.0000x reference)
//
#include <hip/hip_runtime.h>
#include <hip/hip_cooperative_groups.h>
#include <hip/hip_bf16.h>
#include <stdint.h>

namespace cg = cooperative_groups;

#define T_TOKENS 8192
#define D_DIM    1024
#define NE       10
#define NT       8
#define SEG      2048   // padded per-expert list capacity (actual ~1638+-40)

typedef unsigned short u16;
typedef __attribute__((ext_vector_type(8))) __bf16 bf16x8;
typedef __attribute__((ext_vector_type(4))) float  f32x4;
typedef __attribute__((ext_vector_type(8))) unsigned short u16x8;
typedef __attribute__((ext_vector_type(4))) unsigned short u16x4;

static __device__ __forceinline__ u16 f32_to_bf16(float f) {
  union { float f; uint32_t u; } v; v.f = f;
  uint32_t u = v.u;
  return (u16)((u + 0x7fffu + ((u >> 16) & 1u)) >> 16);
}
static __device__ __forceinline__ float bf16_to_f32(u16 u) {
  union { uint32_t u; float f; } v; v.u = ((uint32_t)u) << 16; return v.f;
}

// async 16B global->LDS DMA; LDS dest = wave-uniform base + lane*16 [m97/m104]
static __device__ __forceinline__ void async_load16(const u16* g, u16* l) {
  __builtin_amdgcn_global_load_lds(
      (const __attribute__((address_space(1))) void*)(const void*)g,
      (__attribute__((address_space(3))) void*)(void*)l, 16, 0, 0);
}

// ---------------------------------------------------------------------------
// R10: ONE cooperative kernel, 256 blocks x 512 threads (1 block/CU
// guaranteed co-resident: LDS 74.75KB; R9 measured occupancy ~27% = we
// were effectively at 1 block/CU during gemm anyway). Cross-round algebra
// (R0/R7/R9 totals vs top-5 dispatch bounds) shows ~40-70us of launch/
// dispatch-ramp overhead outside the three kernels; grid.sync() replaces
// two launch boundaries at ~3us each. Phases are the verified R9 code:
//   1a gate (32 tok/block)  1b transpose (8 tiles/block, pad 68->65:
//      stride 65 ≡ 1 mod 32 banks -> conflict-free scalar write+read;
//      pad 68 gave only 8 distinct banks = 8-way write conflict)
//   2  gemm: 2 assignments/block (asg = bx, bx+256 -> same e = bx&7
//      XCD-affinity, same ny, mz and mz+4), R9's 256x128/BK=32 tile,
//      3-slot ring, lookahead-2, issue-then-vmcnt(6), 2 barriers/iter
//   3  combine (32 tok/block), nt stores on write-once out
// ---------------------------------------------------------------------------
union __align__(16) FusedShared {
  struct { u16 As[3][256 * 32]; u16 Bs[3][128 * 32]; int tokS[256]; } m;  // 74.75KB
  struct { float gws[NE * D_DIM]; float gbs[NE]; int se[64]; float swt[64]; } g;
  struct { float tile[64][65]; } t;
};

__global__ __launch_bounds__(512) void fused_moe(
    const float* __restrict__ x, const float* __restrict__ gw,
    const float* __restrict__ gb, const float* __restrict__ W,
    const float* __restrict__ eb, u16* __restrict__ xb, u16* __restrict__ wT,
    int* __restrict__ cnt, int* __restrict__ tokList,
    int* __restrict__ revIdx, float* __restrict__ revW,
    u16* __restrict__ ybuf, float* __restrict__ out) {
  __shared__ FusedShared sh;
  cg::grid_group grid = cg::this_grid();
  int tid  = threadIdx.x;
  int bx   = blockIdx.x;
  int lane = tid & 63;
  int wv   = tid >> 6;              // 0..7

  // ================= phase 1a: gate, 32 tokens/block =================
  {
    const f32x4* g4 = (const f32x4*)gw;
    f32x4* s4 = (f32x4*)sh.g.gws;
    for (int i = tid; i < NE * D_DIM / 4; i += 512) s4[i] = g4[i];
    if (tid < NE) sh.g.gbs[tid] = gb[tid];
  }
  __syncthreads();
  {
    const f32x4* gws4 = (const f32x4*)sh.g.gws;
    for (int it = 0; it < 4; ++it) {
      int slot = wv * 4 + it;       // 0..31
      int t = bx * 32 + slot;
      const f32x4* xr4 = (const f32x4*)(x + (size_t)t * D_DIM);
      f32x4 xv[4];
#pragma unroll
      for (int jj = 0; jj < 4; ++jj) xv[jj] = xr4[lane + 64 * jj];
      u16x4* xbr = (u16x4*)(xb + (size_t)t * D_DIM);
#pragma unroll
      for (int jj = 0; jj < 4; ++jj) {
        u16x4 pk;
#pragma unroll
        for (int k = 0; k < 4; ++k) pk[k] = f32_to_bf16(xv[jj][k]);
        xbr[lane + 64 * jj] = pk;
      }
      float logit[NE];
#pragma unroll
      for (int e = 0; e < NE; ++e) {
        float a = 0.f;
#pragma unroll
        for (int jj = 0; jj < 4; ++jj) {
          f32x4 gv = gws4[e * 256 + lane + 64 * jj];
#pragma unroll
          for (int k = 0; k < 4; ++k) a = fmaf(xv[jj][k], gv[k], a);
        }
#pragma unroll
        for (int off = 32; off >= 1; off >>= 1) a += __shfl_xor(a, off);
        logit[e] = a + sh.g.gbs[e];
      }
      float mx = logit[0];
#pragma unroll
      for (int e = 1; e < NE; ++e) mx = fmaxf(mx, logit[e]);
      float p[NE]; float s = 0.f;
#pragma unroll
      for (int e = 0; e < NE; ++e) { p[e] = expf(logit[e] - mx); s += p[e]; }
      int e0 = 0; float b0 = p[0];
#pragma unroll
      for (int e = 1; e < NE; ++e) if (p[e] > b0) { b0 = p[e]; e0 = e; }
      int e1 = -1; float b1 = -1.f;
#pragma unroll
      for (int e = 0; e < NE; ++e) if (e != e0 && p[e] > b1) { b1 = p[e]; e1 = e; }
      float w0 = b0 / s, w1 = b1 / s;
      float tw0 = (e0 < NT) ? w0 : 0.f;
      float tw1 = (e1 < NT) ? w1 : 0.f;
      float denom = tw0 + tw1;
      float nw0 = 0.f, nw1 = 0.f;
      if (denom > 0.f) { nw0 = tw0 / denom; nw1 = tw1 / denom; }
      if (lane == 0) {
        sh.g.se[slot * 2]     = (e0 < NT) ? e0 : -1;  sh.g.swt[slot * 2]     = nw0;
        sh.g.se[slot * 2 + 1] = (e1 < NT) ? e1 : -1;  sh.g.swt[slot * 2 + 1] = nw1;
        if (e0 >= NT) { revIdx[t * 2]     = -1; revW[t * 2]     = 0.f; }
        if (e1 >= NT) { revIdx[t * 2 + 1] = -1; revW[t * 2 + 1] = 0.f; }
      }
    }
  }
  __syncthreads();
  // compaction: thread e<8 scans 64 (token,slot) entries; one padded atomic.
  if (tid < NT) {
    int e = tid, c = 0;
    for (int i = 0; i < 64; ++i) c += (sh.g.se[i] == e);
    if (c > 0) {
      int base = atomicAdd(&cnt[e * 32], c);
      int j = 0;
      for (int i = 0; i < 64; ++i) {
        if (sh.g.se[i] == e) {
          int tt  = bx * 32 + (i >> 1);
          int pos = base + j;
          tokList[e * SEG + pos]   = tt;
          revIdx[tt * 2 + (i & 1)] = e * SEG + pos;
          revW[tt * 2 + (i & 1)]   = sh.g.swt[i];
          ++j;
        }
      }
    }
  }

  // ================= phase 1b: transpose, 8 tiles/block =================
  {
    int cr = tid & 15;              // col-chunk (load) / k-chunk (store)
    int rr = tid >> 4;              // 0..31
    for (int ti = 0; ti < 8; ++ti) {
      __syncthreads();              // LDS handoff (gate arrays / prev tile)
      int gid = bx * 8 + ti;        // 0..2047
      int e   = gid >> 8;
      int rem = gid & 255;
      int k0  = (rem >> 4) * 64;
      int n0  = (rem & 15) * 64;
      const float* We = W + ((size_t)e << 20);
#pragma unroll
      for (int pass = 0; pass < 2; ++pass) {
        int r = pass * 32 + rr;     // k-row within tile
        f32x4 v = *(const f32x4*)&We[(size_t)(k0 + r) * 1024 + n0 + cr * 4];
#pragma unroll
        for (int j = 0; j < 4; ++j) sh.t.tile[cr * 4 + j][r] = v[j];
      }
      __syncthreads();
      u16* wTe = wT + ((size_t)e << 20);
#pragma unroll
      for (int pass = 0; pass < 2; ++pass) {
        int n = pass * 32 + rr;     // output row (n-dim)
        u16x4 pk;
#pragma unroll
        for (int j = 0; j < 4; ++j) pk[j] = f32_to_bf16(sh.t.tile[n][cr * 4 + j]);
        *(u16x4*)&wTe[(size_t)(n0 + n) * 1024 + k0 + cr * 4] = pk;
      }
    }
  }

  grid.sync();   // xb, wT, cnt, tokList complete device-wide

  // ================= phase 2: gemm, 2 assignments/block =================
  {
    int rl  = lane >> 2;             // 0..15
    int kcp = lane & 3;              // physical chunk slot
    int kcd = kcp ^ ((rl >> 1) & 3); // data chunk fetched (8-row XOR swizzle)
    int wm = wv >> 2, wn = wv & 3;   // 2M x 4N wave grid; per-wave 128x32
    int lrow = lane & 15;
    int q    = lane >> 4;
    int sw   = (q ^ ((lrow >> 1) & 3)) * 8;  // matches 8-row write swizzle
    int rq   = lane >> 4;
    for (int rep = 0; rep < 2; ++rep) {
      __syncthreads();               // LDS handoff (phase 1 / rep 0)
      int asg = bx + rep * 256;
      int e   = asg & 7;             // same XCD both reps (256%8==0)
      int ny  = (asg >> 3) & 7;
      int mz  = asg >> 6;            // rep0: 0..3, rep1: 4..7
      int c   = cnt[e * 32];
      int m0  = mz * 256;
      if (m0 >= c) continue;
      int n0  = ny * 128;
      if (tid < 256) {
        int gm = m0 + tid;
        sh.m.tokS[tid] = (gm < c) ? tokList[e * SEG + gm] : tokList[e * SEG];
      }
      __syncthreads();
      int rowA0 = wv * 32 + rl, rowA1 = rowA0 + 16;
      int rowB  = wv * 16 + rl;
      const u16* gA0 = xb + (size_t)sh.m.tokS[rowA0] * 1024 + kcd * 8;
      const u16* gA1 = xb + (size_t)sh.m.tokS[rowA1] * 1024 + kcd * 8;
      const u16* wTe = wT + ((size_t)e << 20);
      const u16* gB0 = wTe + (size_t)(n0 + rowB) * 1024 + kcd * 8;
      int ldsA0 = (wv * 32) * 32, ldsA1 = ldsA0 + 16 * 32, ldsB0 = (wv * 16) * 32;

      f32x4 acc[8][2];
#pragma unroll
      for (int i = 0; i < 8; ++i)
#pragma unroll
        for (int j = 0; j < 2; ++j) acc[i][j] = (f32x4){0.f, 0.f, 0.f, 0.f};

      // prologue: tiles 0,1 -> slots 0,1 (6 loads in flight per wave)
#pragma unroll
      for (int p = 0; p < 2; ++p) {
        int ko = p * 32;
        async_load16(gA0 + ko, sh.m.As[p] + ldsA0);
        async_load16(gA1 + ko, sh.m.As[p] + ldsA1);
        async_load16(gB0 + ko, sh.m.Bs[p] + ldsB0);
      }
      int cur = 0;                    // slot of tile kt (kt % 3)
      for (int kt = 0; kt < 32; ++kt) {
        // A: all waves done READING slot (kt-1)%3 == slot (kt+2)%3.
        asm volatile("s_barrier" ::: "memory");
        if (kt < 30) {
          int st = cur - 1; if (st < 0) st += 3;   // (kt+2) % 3
          int ko = (kt + 2) * 32;
          async_load16(gA0 + ko, sh.m.As[st] + ldsA0);
          async_load16(gA1 + ko, sh.m.As[st] + ldsA1);
          async_load16(gB0 + ko, sh.m.Bs[st] + ldsB0);
          // 9 outstanding (tiles kt,kt+1,kt+2); wait tile kt's 3 only
          asm volatile("s_waitcnt vmcnt(6)" ::: "memory");
        } else if (kt == 30) {
          asm volatile("s_waitcnt vmcnt(3)" ::: "memory");
        } else {
          asm volatile("s_waitcnt vmcnt(0)" ::: "memory");
        }
        // B: every wave's tile-kt DMA has landed in LDS
        asm volatile("s_barrier" ::: "memory");
        bf16x8 bfr[2];
#pragma unroll
        for (int nt = 0; nt < 2; ++nt)
          bfr[nt] = *(const bf16x8*)(sh.m.Bs[cur] + (wn * 32 + nt * 16 + lrow) * 32 + sw);
#pragma unroll
        for (int mt = 0; mt < 8; ++mt) {
          bf16x8 af = *(const bf16x8*)(sh.m.As[cur] + (wm * 128 + mt * 16 + lrow) * 32 + sw);
#pragma unroll
          for (int nt = 0; nt < 2; ++nt)
            acc[mt][nt] = __builtin_amdgcn_mfma_f32_16x16x32_bf16(
                af, bfr[nt], acc[mt][nt], 0, 0, 0);
        }
        ++cur; if (cur == 3) cur = 0;
      }
      // epilogue: C/D layout col=lane&15, row=(lane>>4)*4+reg [m89]
      float bias[2];
#pragma unroll
      for (int nt = 0; nt < 2; ++nt)
        bias[nt] = eb[e * 1024 + n0 + wn * 32 + nt * 16 + lrow];
      u16* yb = ybuf + ((size_t)(e * SEG + m0)) * 1024 + n0 + wn * 32 + lrow;
#pragma unroll
      for (int mt = 0; mt < 8; ++mt) {
#pragma unroll
        for (int r = 0; r < 4; ++r) {
          int ml = wm * 128 + mt * 16 + rq * 4 + r;
          u16* row = yb + (size_t)ml * 1024;
#pragma unroll
          for (int nt = 0; nt < 2; ++nt)
            row[nt * 16] = f32_to_bf16(acc[mt][nt][r] + bias[nt]);
        }
      }
    }
  }

  grid.sync();   // ybuf complete device-wide

  // ================= phase 3: combine, 32 tokens/block =================
  for (int it = 0; it < 4; ++it) {
    int t  = bx * 32 + wv * 4 + it;
    int i0 = revIdx[t * 2], i1 = revIdx[t * 2 + 1];
    float w0 = revW[t * 2], w1 = revW[t * 2 + 1];
    float o[16];
#pragma unroll
    for (int k = 0; k < 16; ++k) o[k] = 0.f;
    if (i0 >= 0) {
      const u16x8* y = (const u16x8*)(ybuf + (size_t)i0 * 1024);
#pragma unroll
      for (int jj = 0; jj < 2; ++jj) {
        u16x8 v = y[lane + 64 * jj];
#pragma unroll
        for (int k = 0; k < 8; ++k) o[jj * 8 + k] += w0 * bf16_to_f32(v[k]);
      }
    }
    if (i1 >= 0) {
      const u16x8* y = (const u16x8*)(ybuf + (size_t)i1 * 1024);
#pragma unroll
      for (int jj = 0; jj < 2; ++jj) {
        u16x8 v = y[lane + 64 * jj];
#pragma unroll
        for (int k = 0; k < 8; ++k) o[jj * 8 + k] += w1 * bf16_to_f32(v[k]);
      }
    }
    f32x4* o4 = (f32x4*)(out + (size_t)t * 1024);
#pragma unroll
    for (int jj = 0; jj < 2; ++jj)
#pragma unroll
      for (int h = 0; h < 2; ++h) {
        f32x4 vv = {o[jj * 8 + h * 4], o[jj * 8 + h * 4 + 1],
                    o[jj * 8 + h * 4 + 2], o[jj * 8 + h * 4 + 3]};
        __builtin_nontemporal_store(vv, &o4[2 * (lane + 64 * jj) + h]);
      }
  }
}

// ---------------------------------------------------------------------------
// Workspace layout (bytes), total ~64.2 MiB:
//   [0, 4096)        : int cnt[8*32] (one counter per 128B line)
//   [4096, +64K)     : tokList  8*2048 int (combined per-expert lists)
//   [+64K)           : revIdx   8192*2 int
//   [+64K)           : revW     8192*2 float
//   [+16M)           : xb   bf16 [8192][1024]
//   [+16M)           : wT   bf16 [8][1024][1024]
//   [+33.5M)         : ybuf bf16 [8*2048][1024]
// ---------------------------------------------------------------------------
extern "C" void kernel_launch(void* const* d_in, const int* in_sizes, int n_in,
                              void* d_out, int out_size, void* d_ws, size_t ws_size,
                              hipStream_t stream) {
  const float* x  = (const float*)d_in[0];
  const float* gw = (const float*)d_in[1];
  const float* gb = (const float*)d_in[2];
  const float* ew = (const float*)d_in[3];
  const float* eb = (const float*)d_in[4];
  float* out = (float*)d_out;
  char* ws = (char*)d_ws;
  int*   cnt     = (int*)ws;
  int*   tokList = (int*)(ws + 4096);
  int*   revIdx  = (int*)(ws + 4096 + 65536);
  float* revW    = (float*)(ws + 4096 + 131072);
  u16*   xb      = (u16*)(ws + 200704);
  u16*   wT      = (u16*)(ws + 200704 + 16777216);
  u16*   ybuf    = (u16*)(ws + 200704 + 33554432);

  hipMemsetAsync(cnt, 0, 4096, stream);
  void* args[] = {(void*)&x, (void*)&gw, (void*)&gb, (void*)&ew, (void*)&eb,
                  (void*)&xb, (void*)&wT, (void*)&cnt, (void*)&tokList,
                  (void*)&revIdx, (void*)&revW, (void*)&ybuf, (void*)&out};
  hipLaunchCooperativeKernel((const void*)fused_moe, dim3(256), dim3(512),
                             args, 0, stream);
}

// Round 8
// 174.671 us; speedup vs baseline: 1.5264x; 1.5264x over previous
//
#include <hip/hip_runtime.h>
#include <hip/hip_bf16.h>
#include <stdint.h>

#define T_TOKENS 8192
#define D_DIM    1024
#define NE       10
#define NT       8
#define SEG      2048   // padded per-expert list capacity (actual ~1638+-40)

typedef unsigned short u16;
typedef __attribute__((ext_vector_type(8))) __bf16 bf16x8;
typedef __attribute__((ext_vector_type(4))) float  f32x4;
typedef __attribute__((ext_vector_type(8))) unsigned short u16x8;
typedef __attribute__((ext_vector_type(4))) unsigned short u16x4;

static __device__ __forceinline__ u16 f32_to_bf16(float f) {
  union { float f; uint32_t u; } v; v.f = f;
  uint32_t u = v.u;
  return (u16)((u + 0x7fffu + ((u >> 16) & 1u)) >> 16);
}
static __device__ __forceinline__ float bf16_to_f32(u16 u) {
  union { uint32_t u; float f; } v; v.u = ((uint32_t)u) << 16; return v.f;
}

// async 16B global->LDS DMA; LDS dest = wave-uniform base + lane*16 [m97/m104]
static __device__ __forceinline__ void async_load16(const u16* g, u16* l) {
  __builtin_amdgcn_global_load_lds(
      (const __attribute__((address_space(1))) void*)(const void*)g,
      (__attribute__((address_space(3))) void*)(void*)l, 16, 0, 0);
}

// ---------------------------------------------------------------------------
// R11 NOTE (cross-round model): R10's cooperative fusion measured the
// harness's FIXED launch overhead at ~100us (fused kernel 162 vs total 266;
// same constant back-fits R0/R7/R9). Controllable kernel time is only
// ~75us: gemm 45 + prep ~12 + combine ~14 + memset/gaps. So all effort
// goes to gemm. Structure reverted to the verified R9 3-kernel form.
// (R7 bench was an infra flake — "container failed twice", same as R3;
// R3's identical resubmit then passed. Kernel re-audited: all barriers
// block-uniform, ring-slot ordering proven, vmcnt unchanged. Resubmit.)
// ---------------------------------------------------------------------------

// ---------------------------------------------------------------------------
// Kernel 1: prep = gate + weight-transpose fused (independent, BW-bound).
//   blockIdx.x <  1024 : gate role (8 tokens/block)
//   1024..3071         : transpose role (64x64 fp32->bf16 tile of W)
// ---------------------------------------------------------------------------
union PrepShared {
  struct { float gws[NE * D_DIM]; float gbs[NE]; int se[16]; float swt[16]; } g;
  struct { float tile[64][68]; } t;
};

__global__ __launch_bounds__(256) void prep_kernel(
    const float* __restrict__ x, const float* __restrict__ gw,
    const float* __restrict__ gb, const float* __restrict__ W,
    u16* __restrict__ xb, u16* __restrict__ wT,
    int* __restrict__ cnt, int* __restrict__ tokList,
    int* __restrict__ revIdx, float* __restrict__ revW) {
  __shared__ PrepShared sh;
  int tid = threadIdx.x;

  if (blockIdx.x >= 1024) {
    // ---- transpose role: W [e][d][j] fp32 -> wT [e][j][d] bf16 ----
    int tb = blockIdx.x - 1024;
    int e  = tb >> 8;
    int rem = tb & 255;
    int k0 = (rem >> 4) * 64;
    int n0 = (rem & 15) * 64;
    int cr = tid & 15;            // col-chunk (load) / k-chunk (store)
    int r0 = tid >> 4;            // 0..15
    const float* We = W + ((size_t)e << 20);
#pragma unroll
    for (int pass = 0; pass < 4; ++pass) {
      int r = pass * 16 + r0;     // k-row within tile
      f32x4 v = *(const f32x4*)&We[(size_t)(k0 + r) * 1024 + n0 + cr * 4];
#pragma unroll
      for (int j = 0; j < 4; ++j) sh.t.tile[cr * 4 + j][r] = v[j];
    }
    __syncthreads();
    u16* wTe = wT + ((size_t)e << 20);
#pragma unroll
    for (int pass = 0; pass < 4; ++pass) {
      int n = pass * 16 + r0;     // output row (n-dim)
      f32x4 tv = *(const f32x4*)&sh.t.tile[n][cr * 4];
      u16x4 pk;
#pragma unroll
      for (int j = 0; j < 4; ++j) pk[j] = f32_to_bf16(tv[j]);
      *(u16x4*)&wTe[(size_t)(n0 + n) * 1024 + k0 + cr * 4] = pk;
    }
    return;
  }

  // ---- gate role: 8 tokens/block ----
  {
    const f32x4* g4 = (const f32x4*)gw;
    f32x4* s4 = (f32x4*)sh.g.gws;
    for (int i = tid; i < NE * D_DIM / 4; i += 256) s4[i] = g4[i];
  }
  if (tid < NE) sh.g.gbs[tid] = gb[tid];
  __syncthreads();
  int lane = tid & 63;
  int wv   = tid >> 6;
  const f32x4* gws4 = (const f32x4*)sh.g.gws;
  for (int it = 0; it < 2; ++it) {
    int slot = wv * 2 + it;
    int t = blockIdx.x * 8 + slot;
    const f32x4* xr4 = (const f32x4*)(x + (size_t)t * D_DIM);
    f32x4 xv[4];
#pragma unroll
    for (int jj = 0; jj < 4; ++jj) xv[jj] = xr4[lane + 64 * jj];
    u16x4* xbr = (u16x4*)(xb + (size_t)t * D_DIM);
#pragma unroll
    for (int jj = 0; jj < 4; ++jj) {
      u16x4 pk;
#pragma unroll
      for (int k = 0; k < 4; ++k) pk[k] = f32_to_bf16(xv[jj][k]);
      xbr[lane + 64 * jj] = pk;
    }
    float logit[NE];
#pragma unroll
    for (int e = 0; e < NE; ++e) {
      float a = 0.f;
#pragma unroll
      for (int jj = 0; jj < 4; ++jj) {
        f32x4 gv = gws4[e * 256 + lane + 64 * jj];
#pragma unroll
        for (int k = 0; k < 4; ++k) a = fmaf(xv[jj][k], gv[k], a);
      }
#pragma unroll
      for (int off = 32; off >= 1; off >>= 1) a += __shfl_xor(a, off);
      logit[e] = a + sh.g.gbs[e];
    }
    float mx = logit[0];
#pragma unroll
    for (int e = 1; e < NE; ++e) mx = fmaxf(mx, logit[e]);
    float p[NE]; float s = 0.f;
#pragma unroll
    for (int e = 0; e < NE; ++e) { p[e] = expf(logit[e] - mx); s += p[e]; }
    int e0 = 0; float b0 = p[0];
#pragma unroll
    for (int e = 1; e < NE; ++e) if (p[e] > b0) { b0 = p[e]; e0 = e; }
    int e1 = -1; float b1 = -1.f;
#pragma unroll
    for (int e = 0; e < NE; ++e) if (e != e0 && p[e] > b1) { b1 = p[e]; e1 = e; }
    float w0 = b0 / s, w1 = b1 / s;
    float tw0 = (e0 < NT) ? w0 : 0.f;
    float tw1 = (e1 < NT) ? w1 : 0.f;
    float denom = tw0 + tw1;
    float nw0 = 0.f, nw1 = 0.f;
    if (denom > 0.f) { nw0 = tw0 / denom; nw1 = tw1 / denom; }
    if (lane == 0) {
      sh.g.se[slot * 2]     = (e0 < NT) ? e0 : -1;  sh.g.swt[slot * 2]     = nw0;
      sh.g.se[slot * 2 + 1] = (e1 < NT) ? e1 : -1;  sh.g.swt[slot * 2 + 1] = nw1;
      if (e0 >= NT) { revIdx[t * 2]     = -1; revW[t * 2]     = 0.f; }
      if (e1 >= NT) { revIdx[t * 2 + 1] = -1; revW[t * 2 + 1] = 0.f; }
    }
  }
  __syncthreads();
  // compaction: thread e<8 scans 16 (token,slot) entries; one padded atomic.
  if (tid < NT) {
    int e = tid, c = 0;
    for (int i = 0; i < 16; ++i) c += (sh.g.se[i] == e);
    if (c > 0) {
      int base = atomicAdd(&cnt[e * 32], c);
      int j = 0;
      for (int i = 0; i < 16; ++i) {
        if (sh.g.se[i] == e) {
          int tt  = blockIdx.x * 8 + (i >> 1);
          int pos = base + j;
          tokList[e * SEG + pos]   = tt;
          revIdx[tt * 2 + (i & 1)] = e * SEG + pos;
          revW[tt * 2 + (i & 1)]   = sh.g.swt[i];
          ++j;
        }
      }
    }
  }
}

// ---------------------------------------------------------------------------
// Kernel 2: per-expert gathered GEMM. grid x=expert (XCD-affine).
// Tile 256x128 (MxN), BK=32, 8 waves (2M x 4N, per-wave 128x32, acc 8x2).
// Staging/sync skeleton = verified R9: 3-slot ring, lookahead-2,
// issue-then-counted-vmcnt(6), 8-row XOR swizzle (conflicts = 0).
// R11 change (T3-lite + T5, m218b/m224/m248): the 16-MFMA compute region
// is split into 4 phases of 4 MFMAs. Each phase: ds_read-prefetch the NEXT
// phase's A-fragments, then setprio(1) [4 MFMA] setprio(0), then s_barrier.
// Mechanism: per-phase barriers stagger the 4 waves/SIMD into
// {ds_read-issuing} vs {MFMA-executing} roles so the MFMA pipe stays fed
// (null at 2-phase per m190/m230; +10% grouped-GEMM at 8-phase per m248v2;
// setprio pays only with this role split, m218b). DMA issue + vmcnt
// unchanged; everything outside the K-loop byte-identical to R9.
// ---------------------------------------------------------------------------
__global__ __launch_bounds__(512) void moe_gemm(
    const u16* __restrict__ xb, const u16* __restrict__ wT,
    const int* __restrict__ cnt, const int* __restrict__ tokList,
    const float* __restrict__ eb, u16* __restrict__ ybuf) {
  int e  = blockIdx.x;
  int c  = cnt[e * 32];
  int m0 = blockIdx.z * 256;
  if (m0 >= c) return;
  int n0 = blockIdx.y * 128;
  __shared__ __align__(16) u16 As[3][256 * 32];
  __shared__ __align__(16) u16 Bs[3][128 * 32];
  __shared__ int tokS[256];
  int tid = threadIdx.x;
  if (tid < 256) {
    int gm = m0 + tid;
    tokS[tid] = (gm < c) ? tokList[e * SEG + gm] : tokList[e * SEG];
  }
  __syncthreads();
  int lane = tid & 63;
  int wv   = tid >> 6;            // 0..7
  int rl  = lane >> 2;             // 0..15
  int kcp = lane & 3;              // physical chunk slot
  int kcd = kcp ^ ((rl >> 1) & 3); // data chunk fetched (8-row XOR swizzle)
  // staging: A rows [wv*32, wv*32+32) via two 16-row DMAs; B rows [wv*16,+16)
  int rowA0 = wv * 32 + rl, rowA1 = rowA0 + 16;
  int rowB  = wv * 16 + rl;
  const u16* gA0 = xb + (size_t)tokS[rowA0] * 1024 + kcd * 8;
  const u16* gA1 = xb + (size_t)tokS[rowA1] * 1024 + kcd * 8;
  const u16* wTe = wT + ((size_t)e << 20);
  const u16* gB0 = wTe + (size_t)(n0 + rowB) * 1024 + kcd * 8;
  int ldsA0 = (wv * 32) * 32, ldsA1 = ldsA0 + 16 * 32, ldsB0 = (wv * 16) * 32;

  int wm = wv >> 2, wn = wv & 3;   // 2M x 4N wave grid; per-wave 128x32
  int lrow = lane & 15;
  int q    = lane >> 4;
  int sw   = (q ^ ((lrow >> 1) & 3)) * 8;   // matches 8-row write swizzle
  f32x4 acc[8][2];
#pragma unroll
  for (int i = 0; i < 8; ++i)
#pragma unroll
    for (int j = 0; j < 2; ++j) acc[i][j] = (f32x4){0.f, 0.f, 0.f, 0.f};

  // prologue: tiles 0,1 -> slots 0,1 (6 loads in flight per wave)
#pragma unroll
  for (int p = 0; p < 2; ++p) {
    int ko = p * 32;
    async_load16(gA0 + ko, As[p] + ldsA0);
    async_load16(gA1 + ko, As[p] + ldsA1);
    async_load16(gB0 + ko, Bs[p] + ldsB0);
  }

  int cur = 0;                       // slot of tile kt (kt % 3)
  for (int kt = 0; kt < 32; ++kt) {
    // top barrier: all waves consumed slot (kt-1)%3 == (kt+2)%3 (their
    // phase-3 MFMAs executed -> ds_reads complete before their barriers).
    asm volatile("s_barrier" ::: "memory");
    if (kt < 30) {
      int st = cur - 1; if (st < 0) st += 3;   // (kt+2) % 3
      int ko = (kt + 2) * 32;
      async_load16(gA0 + ko, As[st] + ldsA0);
      async_load16(gA1 + ko, As[st] + ldsA1);
      async_load16(gB0 + ko, Bs[st] + ldsB0);
      // 9 outstanding (tiles kt,kt+1,kt+2); wait tile kt's 3 only
      asm volatile("s_waitcnt vmcnt(6)" ::: "memory");
    } else if (kt == 30) {
      asm volatile("s_waitcnt vmcnt(3)" ::: "memory");
    } else {
      asm volatile("s_waitcnt vmcnt(0)" ::: "memory");
    }
    // tile kt landed block-wide
    asm volatile("s_barrier" ::: "memory");
    const u16* Ab = As[cur];
    const u16* Bb = Bs[cur];
    bf16x8 bfr[2];
#pragma unroll
    for (int nt = 0; nt < 2; ++nt)
      bfr[nt] = *(const bf16x8*)(Bb + (wn * 32 + nt * 16 + lrow) * 32 + sw);
    bf16x8 afA, afB, afC, afD;
    afA = *(const bf16x8*)(Ab + (wm * 128 + 0 * 16 + lrow) * 32 + sw);
    afB = *(const bf16x8*)(Ab + (wm * 128 + 1 * 16 + lrow) * 32 + sw);
    // ---- phase 0: prefetch group1, MFMA group0 ----
    afC = *(const bf16x8*)(Ab + (wm * 128 + 2 * 16 + lrow) * 32 + sw);
    afD = *(const bf16x8*)(Ab + (wm * 128 + 3 * 16 + lrow) * 32 + sw);
    __builtin_amdgcn_s_setprio(1);
    acc[0][0] = __builtin_amdgcn_mfma_f32_16x16x32_bf16(afA, bfr[0], acc[0][0], 0, 0, 0);
    acc[0][1] = __builtin_amdgcn_mfma_f32_16x16x32_bf16(afA, bfr[1], acc[0][1], 0, 0, 0);
    acc[1][0] = __builtin_amdgcn_mfma_f32_16x16x32_bf16(afB, bfr[0], acc[1][0], 0, 0, 0);
    acc[1][1] = __builtin_amdgcn_mfma_f32_16x16x32_bf16(afB, bfr[1], acc[1][1], 0, 0, 0);
    __builtin_amdgcn_s_setprio(0);
    asm volatile("s_barrier" ::: "memory");
    // ---- phase 1: prefetch group2, MFMA group1 ----
    afA = *(const bf16x8*)(Ab + (wm * 128 + 4 * 16 + lrow) * 32 + sw);
    afB = *(const bf16x8*)(Ab + (wm * 128 + 5 * 16 + lrow) * 32 + sw);
    __builtin_amdgcn_s_setprio(1);
    acc[2][0] = __builtin_amdgcn_mfma_f32_16x16x32_bf16(afC, bfr[0], acc[2][0], 0, 0, 0);
    acc[2][1] = __builtin_amdgcn_mfma_f32_16x16x32_bf16(afC, bfr[1], acc[2][1], 0, 0, 0);
    acc[3][0] = __builtin_amdgcn_mfma_f32_16x16x32_bf16(afD, bfr[0], acc[3][0], 0, 0, 0);
    acc[3][1] = __builtin_amdgcn_mfma_f32_16x16x32_bf16(afD, bfr[1], acc[3][1], 0, 0, 0);
    __builtin_amdgcn_s_setprio(0);
    asm volatile("s_barrier" ::: "memory");
    // ---- phase 2: prefetch group3, MFMA group2 ----
    afC = *(const bf16x8*)(Ab + (wm * 128 + 6 * 16 + lrow) * 32 + sw);
    afD = *(const bf16x8*)(Ab + (wm * 128 + 7 * 16 + lrow) * 32 + sw);
    __builtin_amdgcn_s_setprio(1);
    acc[4][0] = __builtin_amdgcn_mfma_f32_16x16x32_bf16(afA, bfr[0], acc[4][0], 0, 0, 0);
    acc[4][1] = __builtin_amdgcn_mfma_f32_16x16x32_bf16(afA, bfr[1], acc[4][1], 0, 0, 0);
    acc[5][0] = __builtin_amdgcn_mfma_f32_16x16x32_bf16(afB, bfr[0], acc[5][0], 0, 0, 0);
    acc[5][1] = __builtin_amdgcn_mfma_f32_16x16x32_bf16(afB, bfr[1], acc[5][1], 0, 0, 0);
    __builtin_amdgcn_s_setprio(0);
    asm volatile("s_barrier" ::: "memory");
    // ---- phase 3: MFMA group3 (next iter's top barrier closes it) ----
    __builtin_amdgcn_s_setprio(1);
    acc[6][0] = __builtin_amdgcn_mfma_f32_16x16x32_bf16(afC, bfr[0], acc[6][0], 0, 0, 0);
    acc[6][1] = __builtin_amdgcn_mfma_f32_16x16x32_bf16(afC, bfr[1], acc[6][1], 0, 0, 0);
    acc[7][0] = __builtin_amdgcn_mfma_f32_16x16x32_bf16(afD, bfr[0], acc[7][0], 0, 0, 0);
    acc[7][1] = __builtin_amdgcn_mfma_f32_16x16x32_bf16(afD, bfr[1], acc[7][1], 0, 0, 0);
    __builtin_amdgcn_s_setprio(0);
    ++cur; if (cur == 3) cur = 0;
  }
  // epilogue: C/D layout col=lane&15, row=(lane>>4)*4+reg [m89]
  int rq = lane >> 4;
  float bias[2];
#pragma unroll
  for (int nt = 0; nt < 2; ++nt)
    bias[nt] = eb[e * 1024 + n0 + wn * 32 + nt * 16 + lrow];
  u16* yb = ybuf + ((size_t)(e * SEG + m0)) * 1024 + n0 + wn * 32 + lrow;
#pragma unroll
  for (int mt = 0; mt < 8; ++mt) {
#pragma unroll
    for (int r = 0; r < 4; ++r) {
      int ml = wm * 128 + mt * 16 + rq * 4 + r;
      u16* row = yb + (size_t)ml * 1024;
#pragma unroll
      for (int nt = 0; nt < 2; ++nt)
        row[nt * 16] = f32_to_bf16(acc[mt][nt][r] + bias[nt]);
    }
  }
}

// ---------------------------------------------------------------------------
// Kernel 3: combine. out[t] = w0*ybuf[idx0] + w1*ybuf[idx1]  (pure BW).
// 2048 blocks x 4 tokens; ybuf reads cached; out write-once -> nt stores.
// ---------------------------------------------------------------------------
__global__ __launch_bounds__(256) void combine_kernel(
    const u16* __restrict__ ybuf, const int* __restrict__ revIdx,
    const float* __restrict__ revW, float* __restrict__ out) {
  int tid = threadIdx.x, lane = tid & 63, wv = tid >> 6;
  int t  = blockIdx.x * 4 + wv;
  int i0 = revIdx[t * 2], i1 = revIdx[t * 2 + 1];
  float w0 = revW[t * 2], w1 = revW[t * 2 + 1];
  float o[16];
#pragma unroll
  for (int k = 0; k < 16; ++k) o[k] = 0.f;
  if (i0 >= 0) {
    const u16x8* y = (const u16x8*)(ybuf + (size_t)i0 * 1024);
#pragma unroll
    for (int jj = 0; jj < 2; ++jj) {
      u16x8 v = y[lane + 64 * jj];
#pragma unroll
      for (int k = 0; k < 8; ++k) o[jj * 8 + k] += w0 * bf16_to_f32(v[k]);
    }
  }
  if (i1 >= 0) {
    const u16x8* y = (const u16x8*)(ybuf + (size_t)i1 * 1024);
#pragma unroll
    for (int jj = 0; jj < 2; ++jj) {
      u16x8 v = y[lane + 64 * jj];
#pragma unroll
      for (int k = 0; k < 8; ++k) o[jj * 8 + k] += w1 * bf16_to_f32(v[k]);
    }
  }
  f32x4* o4 = (f32x4*)(out + (size_t)t * 1024);
#pragma unroll
  for (int jj = 0; jj < 2; ++jj)
#pragma unroll
    for (int h = 0; h < 2; ++h) {
      f32x4 vv = {o[jj * 8 + h * 4], o[jj * 8 + h * 4 + 1],
                  o[jj * 8 + h * 4 + 2], o[jj * 8 + h * 4 + 3]};
      __builtin_nontemporal_store(vv, &o4[2 * (lane + 64 * jj) + h]);
    }
}

// ---------------------------------------------------------------------------
// Workspace layout (bytes), total ~64.2 MiB:
//   [0, 4096)        : int cnt[8*32] (one counter per 128B line)
//   [4096, +64K)     : tokList  8*2048 int (combined per-expert lists)
//   [+64K)           : revIdx   8192*2 int
//   [+64K)           : revW     8192*2 float
//   [+16M)           : xb   bf16 [8192][1024]
//   [+16M)           : wT   bf16 [8][1024][1024]
//   [+33.5M)         : ybuf bf16 [8*2048][1024]
// ---------------------------------------------------------------------------
extern "C" void kernel_launch(void* const* d_in, const int* in_sizes, int n_in,
                              void* d_out, int out_size, void* d_ws, size_t ws_size,
                              hipStream_t stream) {
  const float* x  = (const float*)d_in[0];
  const float* gw = (const float*)d_in[1];
  const float* gb = (const float*)d_in[2];
  const float* ew = (const float*)d_in[3];
  const float* eb = (const float*)d_in[4];
  float* out = (float*)d_out;
  char* ws = (char*)d_ws;
  int*   cnt     = (int*)ws;
  int*   tokList = (int*)(ws + 4096);
  int*   revIdx  = (int*)(ws + 4096 + 65536);
  float* revW    = (float*)(ws + 4096 + 131072);
  u16*   xb      = (u16*)(ws + 200704);
  u16*   wT      = (u16*)(ws + 200704 + 16777216);
  u16*   ybuf    = (u16*)(ws + 200704 + 33554432);

  hipMemsetAsync(cnt, 0, 4096, stream);
  prep_kernel<<<3072, 256, 0, stream>>>(x, gw, gb, ew, xb, wT, cnt, tokList,
                                        revIdx, revW);
  moe_gemm<<<dim3(8, 8, 8), 512, 0, stream>>>(xb, wT, cnt, tokList, eb, ybuf);
  combine_kernel<<<2048, 256, 0, stream>>>(ybuf, revIdx, revW, out);
}